// Round 2
// baseline (723.558 us; speedup 1.0000x reference)
//
#include <hip/hip_runtime.h>
#include <hip/hip_bf16.h>
#include <stdint.h>

// Problem: B=32, T=2048, E=D=A=1024. All float tensors are FLOAT32 (per
// reference); x_lens is int32. Output = [context (32*1024) ; att (32*2048)] f32.
// Internal GEMM runs bf16 MFMA (2% relative threshold permits this).

typedef __bf16 bf16;
typedef __bf16 bf16x8 __attribute__((ext_vector_type(8)));
typedef float floatx4 __attribute__((ext_vector_type(4)));

#define T_DIM 2048
#define B_DIM 32
#define K_DIM 1024   // E
#define N_DIM 1024   // A
#define M_DIM (B_DIM * T_DIM)

__device__ __forceinline__ float fast_tanh(float x) {
    float ax = fabsf(x);
    float e  = __expf(ax + ax);          // exp(2|x|); inf for large -> t=1
    float t  = 1.f - 2.f / (e + 1.f);
    return copysignf(t, x);
}

// ------------- W_enc f32 [E,A] -> W_encT bf16 [A,E] -------------------------
__global__ __launch_bounds__(256) void transpose_wenc(
        const float* __restrict__ W, bf16* __restrict__ WT) {
    __shared__ bf16 tile[64][65];
    const int e0 = blockIdx.x * 64, a0 = blockIdx.y * 64;
    const int c = threadIdx.x & 63, r0 = threadIdx.x >> 6;
#pragma unroll
    for (int p = 0; p < 16; ++p) {
        int r = p * 4 + r0;
        tile[r][c] = (bf16)W[(size_t)(e0 + r) * 1024 + a0 + c];
    }
    __syncthreads();
#pragma unroll
    for (int p = 0; p < 16; ++p) {
        int r = p * 4 + r0;
        WT[(size_t)(a0 + r) * 1024 + e0 + c] = tile[c][r];
    }
}

// ------------- dec_proj[b,a] = b_enc[a] + sum_d dec[b,d] W_dec[d,a] ---------
__global__ __launch_bounds__(256) void decproj_kernel(
        const float* __restrict__ dec, const float* __restrict__ Wdec,
        const float* __restrict__ benc, float* __restrict__ dproj) {
    const int b = blockIdx.x;
    const int a = blockIdx.y * 256 + threadIdx.x;
    __shared__ float sdec[1024];
    for (int i = threadIdx.x; i < 1024; i += 256) sdec[i] = dec[b * 1024 + i];
    __syncthreads();
    float acc = benc[a];
#pragma unroll 8
    for (int d = 0; d < 1024; ++d) acc += sdec[d] * Wdec[(size_t)d * 1024 + a];
    dproj[b * 1024 + a] = acc;
}

// ------------- fused energy GEMM + tanh + v-dot -----------------------------
// part[nchunk][m] = sum over this chunk's 128 cols of v[a]*tanh(enc@W + dproj)
__global__ __launch_bounds__(256) void energy_gemm(
        const float* __restrict__ enc, const bf16* __restrict__ WT,
        const float* __restrict__ dproj, const float* __restrict__ v,
        float* __restrict__ part) {
    __shared__ __align__(16) bf16 As[128 * 32];
    __shared__ __align__(16) bf16 Bs[128 * 32];
    __shared__ float esum[128];

    const int tid  = threadIdx.x;
    const int lane = tid & 63;
    const int wave = tid >> 6;
    const int wy = wave >> 1, wx = wave & 1;
    const int n0 = blockIdx.x * 128;          // n fast -> enc tile L2 reuse
    const int m0 = blockIdx.y * 128;
    const int b  = m0 >> 11;

    if (tid < 128) esum[tid] = 0.f;

    floatx4 acc[4][4];
#pragma unroll
    for (int i = 0; i < 4; ++i)
#pragma unroll
        for (int j = 0; j < 4; ++j) acc[i][j] = (floatx4){0.f, 0.f, 0.f, 0.f};

    // staging addressing: thread t covers rows (t>>2) and 64+(t>>2),
    // cols (t&3)*8 .. +8 of the 32-wide K chunk. LDS writes are
    // lane-contiguous 16B chunks (byte offset = 16*lane) -> conflict-free.
    const int sr = tid >> 2;            // 0..63
    const int sc = (tid & 3) * 8;       // 0,8,16,24
    const float* gA = enc + (size_t)(m0 + sr) * 1024 + sc;
    const bf16*  gB = WT  + (size_t)(n0 + sr) * 1024 + sc;
    bf16* lA = As + sr * 32 + sc;
    bf16* lB = Bs + sr * 32 + sc;

    for (int k0 = 0; k0 < K_DIM; k0 += 32) {
        __syncthreads();                      // prev MFMA reads done
#pragma unroll
        for (int rep = 0; rep < 2; ++rep) {
            const float4* p = (const float4*)(gA + (size_t)rep * 64 * 1024 + k0);
            float4 f0 = p[0], f1 = p[1];
            bf16x8 w;
            w[0] = (bf16)f0.x; w[1] = (bf16)f0.y; w[2] = (bf16)f0.z; w[3] = (bf16)f0.w;
            w[4] = (bf16)f1.x; w[5] = (bf16)f1.y; w[6] = (bf16)f1.z; w[7] = (bf16)f1.w;
            *(bf16x8*)(lA + rep * 64 * 32) = w;
            *(bf16x8*)(lB + rep * 64 * 32) =
                *(const bf16x8*)(gB + (size_t)rep * 64 * 1024 + k0);
        }
        __syncthreads();                      // staging visible

        bf16x8 af[4], bfr[4];
#pragma unroll
        for (int i = 0; i < 4; ++i)
            af[i] = *(const bf16x8*)(As + (wy * 64 + i * 16 + (lane & 15)) * 32 + (lane >> 4) * 8);
#pragma unroll
        for (int i = 0; i < 4; ++i)
            bfr[i] = *(const bf16x8*)(Bs + (wx * 64 + i * 16 + (lane & 15)) * 32 + (lane >> 4) * 8);
#pragma unroll
        for (int mi = 0; mi < 4; ++mi)
#pragma unroll
            for (int ni = 0; ni < 4; ++ni)
                acc[mi][ni] = __builtin_amdgcn_mfma_f32_16x16x32_bf16(
                    af[mi], bfr[ni], acc[mi][ni], 0, 0, 0);
    }
    __syncthreads();

    // epilogue: esum[row] += sum_cols v[col]*tanh(acc + dproj[b,col])
    float vv[4], dp[4];
#pragma unroll
    for (int ni = 0; ni < 4; ++ni) {
        int col = n0 + wx * 64 + ni * 16 + (lane & 15);
        vv[ni] = v[col];
        dp[ni] = dproj[b * 1024 + col];
    }
#pragma unroll
    for (int mi = 0; mi < 4; ++mi) {
#pragma unroll
        for (int r = 0; r < 4; ++r) {
            float s = 0.f;
#pragma unroll
            for (int ni = 0; ni < 4; ++ni)
                s += vv[ni] * fast_tanh(acc[mi][ni][r] + dp[ni]);
            s += __shfl_xor(s, 1);
            s += __shfl_xor(s, 2);
            s += __shfl_xor(s, 4);
            s += __shfl_xor(s, 8);
            if ((lane & 15) == 0) {
                int row = wy * 64 + mi * 16 + (lane >> 4) * 4 + r;
                atomicAdd(&esum[row], s);     // LDS atomic, low contention
            }
        }
    }
    __syncthreads();
    if (tid < 128) part[(size_t)blockIdx.x * M_DIM + m0 + tid] = esum[tid];
}

// ------------- masked softmax over T (multiplicative 0/1 mask!) -------------
__global__ __launch_bounds__(256) void softmax_kernel(
        const float* __restrict__ part, const int* __restrict__ xlens,
        float* __restrict__ att) {
    const int b = blockIdx.x, tid = threadIdx.x;
    const int len = xlens[b];
    float e[8];
    float mx = -3.4e38f;
#pragma unroll
    for (int i = 0; i < 8; ++i) {
        const int t = tid + i * 256;
        float s = 0.f;
#pragma unroll
        for (int c = 0; c < 8; ++c) s += part[(size_t)c * M_DIM + b * 2048 + t];
        e[i] = (t < len) ? s : 0.f;           // energy * mask (0s kept in softmax)
        mx = fmaxf(mx, e[i]);
    }
#pragma unroll
    for (int off = 1; off < 64; off <<= 1) mx = fmaxf(mx, __shfl_xor(mx, off));
    __shared__ float sr1[4], sr2[4];
    if ((tid & 63) == 0) sr1[tid >> 6] = mx;
    __syncthreads();
    mx = fmaxf(fmaxf(sr1[0], sr1[1]), fmaxf(sr1[2], sr1[3]));
    float sum = 0.f;
#pragma unroll
    for (int i = 0; i < 8; ++i) { e[i] = __expf(e[i] - mx); sum += e[i]; }
#pragma unroll
    for (int off = 1; off < 64; off <<= 1) sum += __shfl_xor(sum, off);
    if ((tid & 63) == 0) sr2[tid >> 6] = sum;
    __syncthreads();
    sum = sr2[0] + sr2[1] + sr2[2] + sr2[3];
    const float inv = 1.f / sum;
#pragma unroll
    for (int i = 0; i < 8; ++i)
        att[b * 2048 + tid + i * 256] = e[i] * inv;
}

// ------------- context[b,e] = sum_t att[b,t] * enc[b,t,e] -------------------
__global__ __launch_bounds__(256) void context_kernel(
        const float* __restrict__ enc, const float* __restrict__ att,
        float* __restrict__ ctx) {
    const int b = blockIdx.x, t0 = blockIdx.y * 128, tid = threadIdx.x;
    __shared__ float satt[128];
    if (tid < 128) satt[tid] = att[b * 2048 + t0 + tid];
    __syncthreads();
    const float* base = enc + ((size_t)b * 2048 + t0) * 1024 + tid * 4;
    float a0 = 0.f, a1 = 0.f, a2 = 0.f, a3 = 0.f;
    for (int t = 0; t < 128; ++t) {
        float4 ev = *(const float4*)(base + (size_t)t * 1024);
        float w = satt[t];
        a0 += w * ev.x; a1 += w * ev.y; a2 += w * ev.z; a3 += w * ev.w;
    }
    float* o = ctx + b * 1024 + tid * 4;
    atomicAdd(o + 0, a0); atomicAdd(o + 1, a1);
    atomicAdd(o + 2, a2); atomicAdd(o + 3, a3);
}

__global__ __launch_bounds__(256) void copy_ctx(const float* __restrict__ ctx,
                                                float* __restrict__ out) {
    int i = blockIdx.x * 256 + threadIdx.x;
    out[i] = ctx[i];
}

extern "C" void kernel_launch(void* const* d_in, const int* in_sizes, int n_in,
                              void* d_out, int out_size, void* d_ws, size_t ws_size,
                              hipStream_t stream) {
    const float* enc   = (const float*)d_in[0];
    const int*   xlens = (const int*)d_in[1];
    const float* dec   = (const float*)d_in[2];
    // d_in[3] (att_weights_step) unused by reference
    const float* Wenc  = (const float*)d_in[4];
    const float* benc  = (const float*)d_in[5];
    const float* Wdec  = (const float*)d_in[6];
    const float* v     = (const float*)d_in[7];

    float* out_ctx = (float*)d_out;
    float* out_att = out_ctx + B_DIM * K_DIM;      // +32768

    char* ws = (char*)d_ws;
    float* dproj = (float*)ws;                                  // 128 KB
    bf16*  WT    = (bf16*)(ws + (128u << 10));                  // 2 MB
    float* part  = (float*)(ws + (128u << 10) + (2u << 20));    // 2 MB
    float* ctx32 = (float*)(ws + (128u << 10) + (4u << 20));    // 128 KB
    // total ws usage: ~4.25 MB

    hipMemsetAsync(ctx32, 0, B_DIM * K_DIM * sizeof(float), stream);

    transpose_wenc<<<dim3(16, 16), 256, 0, stream>>>(Wenc, WT);
    decproj_kernel<<<dim3(B_DIM, 4), 256, 0, stream>>>(dec, Wdec, benc, dproj);
    // n-chunk fast (x), m-tile slow (y): 8 co-resident blocks share one enc tile
    energy_gemm<<<dim3(N_DIM / 128, M_DIM / 128), 256, 0, stream>>>(enc, WT, dproj, v, part);
    softmax_kernel<<<B_DIM, 256, 0, stream>>>(part, xlens, out_att);
    context_kernel<<<dim3(B_DIM, 16), 256, 0, stream>>>(enc, out_att, ctx32);
    copy_ctx<<<B_DIM * K_DIM / 256, 256, 0, stream>>>(ctx32, out_ctx);
}

// Round 3
// 712.110 us; speedup vs baseline: 1.0161x; 1.0161x over previous
//
#include <hip/hip_runtime.h>
#include <hip/hip_bf16.h>
#include <stdint.h>

// B=32, T=2048, E=D=A=1024. f32 I/O; x_lens int32.
// Output = [context (32*1024) ; att (32*2048)] f32.
// Internal energy GEMM: bf16 MFMA, m97 structure (global_load_lds w=16),
// XCD-aware swizzle so n-chunks of one m-tile share an XCD L2.

typedef __bf16 bf16;
typedef __bf16 bf16x8 __attribute__((ext_vector_type(8)));
typedef float floatx4 __attribute__((ext_vector_type(4)));

#define T_DIM 2048
#define B_DIM 32
#define K_DIM 1024   // E
#define N_DIM 1024   // A
#define M_DIM (B_DIM * T_DIM)
#define ENC_ELEMS ((size_t)M_DIM * K_DIM)   // 64M

__device__ __forceinline__ void async_copy16(const bf16* g, bf16* l) {
    __builtin_amdgcn_global_load_lds(
        (const __attribute__((address_space(1))) void*)g,
        (__attribute__((address_space(3))) void*)l, 16, 0, 0);
}

__device__ __forceinline__ float fast_tanh(float x) {
    float ax = fabsf(x);
    float e  = __expf(ax + ax);
    float t  = 1.f - 2.f / (e + 1.f);
    return copysignf(t, x);
}

// ------------- enc f32 -> bf16 (contiguous) ---------------------------------
__global__ __launch_bounds__(256) void cvt_enc(const float* __restrict__ in,
                                               bf16* __restrict__ out) {
    size_t i = ((size_t)blockIdx.x * 256 + threadIdx.x) * 8;
    const size_t stride = (size_t)gridDim.x * 256 * 8;
    for (; i < ENC_ELEMS; i += stride) {
        float4 f0 = *(const float4*)(in + i);
        float4 f1 = *(const float4*)(in + i + 4);
        bf16x8 w;
        w[0] = (bf16)f0.x; w[1] = (bf16)f0.y; w[2] = (bf16)f0.z; w[3] = (bf16)f0.w;
        w[4] = (bf16)f1.x; w[5] = (bf16)f1.y; w[6] = (bf16)f1.z; w[7] = (bf16)f1.w;
        *(bf16x8*)(out + i) = w;
    }
}

// ------------- W_enc f32 [E,A] -> W_encT bf16 [A,E] -------------------------
__global__ __launch_bounds__(256) void transpose_wenc(
        const float* __restrict__ W, bf16* __restrict__ WT) {
    __shared__ bf16 tile[64][65];
    const int e0 = blockIdx.x * 64, a0 = blockIdx.y * 64;
    const int c = threadIdx.x & 63, r0 = threadIdx.x >> 6;
#pragma unroll
    for (int p = 0; p < 16; ++p) {
        int r = p * 4 + r0;
        tile[r][c] = (bf16)W[(size_t)(e0 + r) * 1024 + a0 + c];
    }
    __syncthreads();
#pragma unroll
    for (int p = 0; p < 16; ++p) {
        int r = p * 4 + r0;
        WT[(size_t)(a0 + r) * 1024 + e0 + c] = tile[c][r];
    }
}

// ------------- dec_proj[b,a] = b_enc[a] + sum_d dec[b,d] W_dec[d,a] ---------
__global__ __launch_bounds__(256) void decproj_kernel(
        const float* __restrict__ dec, const float* __restrict__ Wdec,
        const float* __restrict__ benc, float* __restrict__ dproj) {
    const int b = blockIdx.x;
    const int a = blockIdx.y * 256 + threadIdx.x;
    __shared__ float sdec[1024];
    for (int i = threadIdx.x; i < 1024; i += 256) sdec[i] = dec[b * 1024 + i];
    __syncthreads();
    float acc = benc[a];
#pragma unroll 8
    for (int d = 0; d < 1024; ++d) acc += sdec[d] * Wdec[(size_t)d * 1024 + a];
    dproj[b * 1024 + a] = acc;
}

// ------------- fused energy GEMM (bf16 A via global_load_lds) ---------------
// part[n_chunk][m] = sum over chunk's 128 cols of v[a]*tanh(enc@W + dproj)
__global__ __launch_bounds__(256) void energy_gemm_bf16(
        const bf16* __restrict__ encb, const bf16* __restrict__ WT,
        const float* __restrict__ dproj, const float* __restrict__ v,
        float* __restrict__ part) {
    __shared__ __align__(16) bf16 As[128 * 32];
    __shared__ __align__(16) bf16 Bs[128 * 32];
    __shared__ float esum[128];

    const int tid  = threadIdx.x;
    const int lane = tid & 63;
    const int wave = tid >> 6;
    const int wy = wave >> 1, wx = wave & 1;

    // XCD-aware swizzle: consecutive block IDs round-robin the 8 XCDs, so put
    // all 8 n-chunks of one m-tile on ONE xcd, consecutive in dispatch time.
    const int L = blockIdx.x;            // 0..4095
    const int xcd  = L & 7;
    const int slot = L >> 3;             // 0..511
    const int m_tile = xcd * 64 + (slot >> 3);   // 0..511
    const int n_chunk = slot & 7;                // 0..7
    const int m0 = m_tile * 128;
    const int n0 = n_chunk * 128;
    const int b  = m0 >> 11;

    if (tid < 128) esum[tid] = 0.f;

    floatx4 acc[4][4];
#pragma unroll
    for (int i = 0; i < 4; ++i)
#pragma unroll
        for (int j = 0; j < 4; ++j) acc[i][j] = (floatx4){0.f, 0.f, 0.f, 0.f};

    // staging: wave w stages rows [w*32, w*32+32). Lane l covers row w*32+i*16+(l>>2),
    // cols (l&3)*8..+8. LDS dest = wave-uniform base + lane*16 (HW rule).
    const bf16* gA = encb + (size_t)(m0 + wave * 32 + (lane >> 2)) * 1024 + (lane & 3) * 8;
    const bf16* gB = WT   + (size_t)(n0 + wave * 32 + (lane >> 2)) * 1024 + (lane & 3) * 8;
    bf16* lA = As + wave * 1024;   // bytes: wave*2048; issue i adds 1024B (512 elems)
    bf16* lB = Bs + wave * 1024;

    for (int k0 = 0; k0 < K_DIM; k0 += 32) {
        __syncthreads();                      // prev MFMA reads done
        async_copy16(gA + k0, lA);
        async_copy16(gA + (size_t)16 * 1024 + k0, lA + 512);
        async_copy16(gB + k0, lB);
        async_copy16(gB + (size_t)16 * 1024 + k0, lB + 512);
        __syncthreads();                      // drains vmcnt -> LDS valid

        bf16x8 af[4], bfr[4];
#pragma unroll
        for (int i = 0; i < 4; ++i)
            af[i] = *(const bf16x8*)(As + (wy * 64 + i * 16 + (lane & 15)) * 32 + (lane >> 4) * 8);
#pragma unroll
        for (int i = 0; i < 4; ++i)
            bfr[i] = *(const bf16x8*)(Bs + (wx * 64 + i * 16 + (lane & 15)) * 32 + (lane >> 4) * 8);
#pragma unroll
        for (int mi = 0; mi < 4; ++mi)
#pragma unroll
            for (int ni = 0; ni < 4; ++ni)
                acc[mi][ni] = __builtin_amdgcn_mfma_f32_16x16x32_bf16(
                    af[mi], bfr[ni], acc[mi][ni], 0, 0, 0);
    }
    __syncthreads();

    float vv[4], dp[4];
#pragma unroll
    for (int ni = 0; ni < 4; ++ni) {
        int col = n0 + wx * 64 + ni * 16 + (lane & 15);
        vv[ni] = v[col];
        dp[ni] = dproj[b * 1024 + col];
    }
#pragma unroll
    for (int mi = 0; mi < 4; ++mi) {
#pragma unroll
        for (int r = 0; r < 4; ++r) {
            float s = 0.f;
#pragma unroll
            for (int ni = 0; ni < 4; ++ni)
                s += vv[ni] * fast_tanh(acc[mi][ni][r] + dp[ni]);
            s += __shfl_xor(s, 1);
            s += __shfl_xor(s, 2);
            s += __shfl_xor(s, 4);
            s += __shfl_xor(s, 8);
            if ((lane & 15) == 0) {
                int row = wy * 64 + mi * 16 + (lane >> 4) * 4 + r;
                atomicAdd(&esum[row], s);
            }
        }
    }
    __syncthreads();
    if (tid < 128) part[(size_t)n_chunk * M_DIM + m0 + tid] = esum[tid];
}

// ------------- fallback (f32 A staged through VALU) — round-2 path ----------
__global__ __launch_bounds__(256) void energy_gemm_f32(
        const float* __restrict__ enc, const bf16* __restrict__ WT,
        const float* __restrict__ dproj, const float* __restrict__ v,
        float* __restrict__ part) {
    __shared__ __align__(16) bf16 As[128 * 32];
    __shared__ __align__(16) bf16 Bs[128 * 32];
    __shared__ float esum[128];

    const int tid  = threadIdx.x;
    const int lane = tid & 63;
    const int wave = tid >> 6;
    const int wy = wave >> 1, wx = wave & 1;
    const int L = blockIdx.x;
    const int xcd  = L & 7;
    const int slot = L >> 3;
    const int m_tile = xcd * 64 + (slot >> 3);
    const int n_chunk = slot & 7;
    const int m0 = m_tile * 128;
    const int n0 = n_chunk * 128;
    const int b  = m0 >> 11;

    if (tid < 128) esum[tid] = 0.f;

    floatx4 acc[4][4];
#pragma unroll
    for (int i = 0; i < 4; ++i)
#pragma unroll
        for (int j = 0; j < 4; ++j) acc[i][j] = (floatx4){0.f, 0.f, 0.f, 0.f};

    const int sr = tid >> 2;
    const int sc = (tid & 3) * 8;
    const float* gA = enc + (size_t)(m0 + sr) * 1024 + sc;
    const bf16*  gB = WT  + (size_t)(n0 + sr) * 1024 + sc;
    bf16* lA = As + sr * 32 + sc;
    bf16* lB = Bs + sr * 32 + sc;

    for (int k0 = 0; k0 < K_DIM; k0 += 32) {
        __syncthreads();
#pragma unroll
        for (int rep = 0; rep < 2; ++rep) {
            const float4* p = (const float4*)(gA + (size_t)rep * 64 * 1024 + k0);
            float4 f0 = p[0], f1 = p[1];
            bf16x8 w;
            w[0] = (bf16)f0.x; w[1] = (bf16)f0.y; w[2] = (bf16)f0.z; w[3] = (bf16)f0.w;
            w[4] = (bf16)f1.x; w[5] = (bf16)f1.y; w[6] = (bf16)f1.z; w[7] = (bf16)f1.w;
            *(bf16x8*)(lA + rep * 64 * 32) = w;
            *(bf16x8*)(lB + rep * 64 * 32) =
                *(const bf16x8*)(gB + (size_t)rep * 64 * 1024 + k0);
        }
        __syncthreads();

        bf16x8 af[4], bfr[4];
#pragma unroll
        for (int i = 0; i < 4; ++i)
            af[i] = *(const bf16x8*)(As + (wy * 64 + i * 16 + (lane & 15)) * 32 + (lane >> 4) * 8);
#pragma unroll
        for (int i = 0; i < 4; ++i)
            bfr[i] = *(const bf16x8*)(Bs + (wx * 64 + i * 16 + (lane & 15)) * 32 + (lane >> 4) * 8);
#pragma unroll
        for (int mi = 0; mi < 4; ++mi)
#pragma unroll
            for (int ni = 0; ni < 4; ++ni)
                acc[mi][ni] = __builtin_amdgcn_mfma_f32_16x16x32_bf16(
                    af[mi], bfr[ni], acc[mi][ni], 0, 0, 0);
    }
    __syncthreads();

    float vv[4], dp[4];
#pragma unroll
    for (int ni = 0; ni < 4; ++ni) {
        int col = n0 + wx * 64 + ni * 16 + (lane & 15);
        vv[ni] = v[col];
        dp[ni] = dproj[b * 1024 + col];
    }
#pragma unroll
    for (int mi = 0; mi < 4; ++mi) {
#pragma unroll
        for (int r = 0; r < 4; ++r) {
            float s = 0.f;
#pragma unroll
            for (int ni = 0; ni < 4; ++ni)
                s += vv[ni] * fast_tanh(acc[mi][ni][r] + dp[ni]);
            s += __shfl_xor(s, 1);
            s += __shfl_xor(s, 2);
            s += __shfl_xor(s, 4);
            s += __shfl_xor(s, 8);
            if ((lane & 15) == 0) {
                int row = wy * 64 + mi * 16 + (lane >> 4) * 4 + r;
                atomicAdd(&esum[row], s);
            }
        }
    }
    __syncthreads();
    if (tid < 128) part[(size_t)n_chunk * M_DIM + m0 + tid] = esum[tid];
}

// ------------- masked softmax over T (multiplicative 0/1 mask) --------------
__global__ __launch_bounds__(256) void softmax_kernel(
        const float* __restrict__ part, const int* __restrict__ xlens,
        float* __restrict__ att) {
    const int b = blockIdx.x, tid = threadIdx.x;
    const int len = xlens[b];
    float e[8];
    float mx = -3.4e38f;
#pragma unroll
    for (int i = 0; i < 8; ++i) {
        const int t = tid + i * 256;
        float s = 0.f;
#pragma unroll
        for (int c = 0; c < 8; ++c) s += part[(size_t)c * M_DIM + b * 2048 + t];
        e[i] = (t < len) ? s : 0.f;
        mx = fmaxf(mx, e[i]);
    }
#pragma unroll
    for (int off = 1; off < 64; off <<= 1) mx = fmaxf(mx, __shfl_xor(mx, off));
    __shared__ float sr1[4], sr2[4];
    if ((tid & 63) == 0) sr1[tid >> 6] = mx;
    __syncthreads();
    mx = fmaxf(fmaxf(sr1[0], sr1[1]), fmaxf(sr1[2], sr1[3]));
    float sum = 0.f;
#pragma unroll
    for (int i = 0; i < 8; ++i) { e[i] = __expf(e[i] - mx); sum += e[i]; }
#pragma unroll
    for (int off = 1; off < 64; off <<= 1) sum += __shfl_xor(sum, off);
    if ((tid & 63) == 0) sr2[tid >> 6] = sum;
    __syncthreads();
    sum = sr2[0] + sr2[1] + sr2[2] + sr2[3];
    const float inv = 1.f / sum;
#pragma unroll
    for (int i = 0; i < 8; ++i)
        att[b * 2048 + tid + i * 256] = e[i] * inv;
}

// ------------- context[b,e] = sum_t att[b,t] * enc[b,t,e]  (f32 enc) --------
__global__ __launch_bounds__(256) void context_kernel(
        const float* __restrict__ enc, const float* __restrict__ att,
        float* __restrict__ ctx) {
    const int b = blockIdx.x, t0 = blockIdx.y * 128, tid = threadIdx.x;
    __shared__ float satt[128];
    if (tid < 128) satt[tid] = att[b * 2048 + t0 + tid];
    __syncthreads();
    const float* base = enc + ((size_t)b * 2048 + t0) * 1024 + tid * 4;
    float a0 = 0.f, a1 = 0.f, a2 = 0.f, a3 = 0.f;
    for (int t = 0; t < 128; ++t) {
        float4 ev = *(const float4*)(base + (size_t)t * 1024);
        float w = satt[t];
        a0 += w * ev.x; a1 += w * ev.y; a2 += w * ev.z; a3 += w * ev.w;
    }
    float* o = ctx + b * 1024 + tid * 4;
    atomicAdd(o + 0, a0); atomicAdd(o + 1, a1);
    atomicAdd(o + 2, a2); atomicAdd(o + 3, a3);
}

extern "C" void kernel_launch(void* const* d_in, const int* in_sizes, int n_in,
                              void* d_out, int out_size, void* d_ws, size_t ws_size,
                              hipStream_t stream) {
    const float* enc   = (const float*)d_in[0];
    const int*   xlens = (const int*)d_in[1];
    const float* dec   = (const float*)d_in[2];
    const float* Wenc  = (const float*)d_in[4];
    const float* benc  = (const float*)d_in[5];
    const float* Wdec  = (const float*)d_in[6];
    const float* v     = (const float*)d_in[7];

    float* out_ctx = (float*)d_out;
    float* out_att = out_ctx + B_DIM * K_DIM;

    char* ws = (char*)d_ws;
    float* dproj = (float*)ws;                                  // 128 KB
    bf16*  WT    = (bf16*)(ws + (128u << 10));                  // 2 MB
    float* part  = (float*)(ws + (128u << 10) + (2u << 20));    // 2 MB
    bf16*  encb  = (bf16*)(ws + (128u << 10) + (4u << 20));     // 128 MB
    const size_t need = (128u << 10) + (4u << 20) + ENC_ELEMS * sizeof(bf16);

    hipMemsetAsync(out_ctx, 0, B_DIM * K_DIM * sizeof(float), stream);

    transpose_wenc<<<dim3(16, 16), 256, 0, stream>>>(Wenc, WT);
    decproj_kernel<<<dim3(B_DIM, 4), 256, 0, stream>>>(dec, Wdec, benc, dproj);

    if (ws_size >= need) {
        cvt_enc<<<2048, 256, 0, stream>>>(enc, encb);
        energy_gemm_bf16<<<4096, 256, 0, stream>>>(encb, WT, dproj, v, part);
    } else {
        energy_gemm_f32<<<4096, 256, 0, stream>>>(enc, WT, dproj, v, part);
    }

    softmax_kernel<<<B_DIM, 256, 0, stream>>>(part, xlens, out_att);
    context_kernel<<<dim3(B_DIM, 16), 256, 0, stream>>>(enc, out_att, out_ctx);
}

// Round 4
// 677.374 us; speedup vs baseline: 1.0682x; 1.0513x over previous
//
#include <hip/hip_runtime.h>
#include <hip/hip_bf16.h>
#include <stdint.h>

// B=32, T=2048, E=D=A=1024. f32 I/O; x_lens int32.
// Output = [context (32*1024) ; att (32*2048)] f32.
// Pipeline: cvt enc->bf16 | W_encT bf16 | dec_proj | bf16-MFMA energy GEMM
// (XCD-swizzled, global_load_lds w=16) | softmax | atomic-free bf16 context.

typedef __bf16 bf16;
typedef __bf16 bf16x8 __attribute__((ext_vector_type(8)));
typedef __bf16 bf16x4 __attribute__((ext_vector_type(4)));
typedef float floatx4 __attribute__((ext_vector_type(4)));

#define T_DIM 2048
#define B_DIM 32
#define K_DIM 1024   // E
#define N_DIM 1024   // A
#define M_DIM (B_DIM * T_DIM)
#define ENC_ELEMS ((size_t)M_DIM * K_DIM)   // 64M

__device__ __forceinline__ void async_copy16(const bf16* g, bf16* l) {
    __builtin_amdgcn_global_load_lds(
        (const __attribute__((address_space(1))) void*)g,
        (__attribute__((address_space(3))) void*)l, 16, 0, 0);
}

__device__ __forceinline__ float fast_tanh(float x) {
    float ax = fabsf(x);
    float e  = __expf(ax + ax);
    float t  = 1.f - 2.f / (e + 1.f);
    return copysignf(t, x);
}

// ------------- enc f32 -> bf16 (contiguous) ---------------------------------
__global__ __launch_bounds__(256) void cvt_enc(const float* __restrict__ in,
                                               bf16* __restrict__ out) {
    size_t i = ((size_t)blockIdx.x * 256 + threadIdx.x) * 8;
    const size_t stride = (size_t)gridDim.x * 256 * 8;
    for (; i < ENC_ELEMS; i += stride) {
        float4 f0 = *(const float4*)(in + i);
        float4 f1 = *(const float4*)(in + i + 4);
        bf16x8 w;
        w[0] = (bf16)f0.x; w[1] = (bf16)f0.y; w[2] = (bf16)f0.z; w[3] = (bf16)f0.w;
        w[4] = (bf16)f1.x; w[5] = (bf16)f1.y; w[6] = (bf16)f1.z; w[7] = (bf16)f1.w;
        *(bf16x8*)(out + i) = w;
    }
}

// ------------- W_enc f32 [E,A] -> W_encT bf16 [A,E] -------------------------
__global__ __launch_bounds__(256) void transpose_wenc(
        const float* __restrict__ W, bf16* __restrict__ WT) {
    __shared__ bf16 tile[64][65];
    const int e0 = blockIdx.x * 64, a0 = blockIdx.y * 64;
    const int c = threadIdx.x & 63, r0 = threadIdx.x >> 6;
#pragma unroll
    for (int p = 0; p < 16; ++p) {
        int r = p * 4 + r0;
        tile[r][c] = (bf16)W[(size_t)(e0 + r) * 1024 + a0 + c];
    }
    __syncthreads();
#pragma unroll
    for (int p = 0; p < 16; ++p) {
        int r = p * 4 + r0;
        WT[(size_t)(a0 + r) * 1024 + e0 + c] = tile[c][r];
    }
}

// ------------- dec_proj[b,a] = b_enc[a] + sum_d dec[b,d] W_dec[d,a] ---------
__global__ __launch_bounds__(256) void decproj_kernel(
        const float* __restrict__ dec, const float* __restrict__ Wdec,
        const float* __restrict__ benc, float* __restrict__ dproj) {
    const int b = blockIdx.x;
    const int a = blockIdx.y * 256 + threadIdx.x;
    __shared__ float sdec[1024];
    for (int i = threadIdx.x; i < 1024; i += 256) sdec[i] = dec[b * 1024 + i];
    __syncthreads();
    float acc = benc[a];
#pragma unroll 8
    for (int d = 0; d < 1024; ++d) acc += sdec[d] * Wdec[(size_t)d * 1024 + a];
    dproj[b * 1024 + a] = acc;
}

// ------------- fused energy GEMM (bf16 A via global_load_lds) ---------------
__global__ __launch_bounds__(256) void energy_gemm_bf16(
        const bf16* __restrict__ encb, const bf16* __restrict__ WT,
        const float* __restrict__ dproj, const float* __restrict__ v,
        float* __restrict__ part) {
    __shared__ __align__(16) bf16 As[128 * 32];
    __shared__ __align__(16) bf16 Bs[128 * 32];
    __shared__ float esum[128];

    const int tid  = threadIdx.x;
    const int lane = tid & 63;
    const int wave = tid >> 6;
    const int wy = wave >> 1, wx = wave & 1;

    // XCD swizzle: all 8 n-chunks of one m-tile land on ONE XCD, consecutive.
    const int L = blockIdx.x;
    const int xcd  = L & 7;
    const int slot = L >> 3;
    const int m_tile = xcd * 64 + (slot >> 3);
    const int n_chunk = slot & 7;
    const int m0 = m_tile * 128;
    const int n0 = n_chunk * 128;
    const int b  = m0 >> 11;

    if (tid < 128) esum[tid] = 0.f;

    floatx4 acc[4][4];
#pragma unroll
    for (int i = 0; i < 4; ++i)
#pragma unroll
        for (int j = 0; j < 4; ++j) acc[i][j] = (floatx4){0.f, 0.f, 0.f, 0.f};

    const bf16* gA = encb + (size_t)(m0 + wave * 32 + (lane >> 2)) * 1024 + (lane & 3) * 8;
    const bf16* gB = WT   + (size_t)(n0 + wave * 32 + (lane >> 2)) * 1024 + (lane & 3) * 8;
    bf16* lA = As + wave * 1024;
    bf16* lB = Bs + wave * 1024;

    for (int k0 = 0; k0 < K_DIM; k0 += 32) {
        __syncthreads();
        async_copy16(gA + k0, lA);
        async_copy16(gA + (size_t)16 * 1024 + k0, lA + 512);
        async_copy16(gB + k0, lB);
        async_copy16(gB + (size_t)16 * 1024 + k0, lB + 512);
        __syncthreads();

        bf16x8 af[4], bfr[4];
#pragma unroll
        for (int i = 0; i < 4; ++i)
            af[i] = *(const bf16x8*)(As + (wy * 64 + i * 16 + (lane & 15)) * 32 + (lane >> 4) * 8);
#pragma unroll
        for (int i = 0; i < 4; ++i)
            bfr[i] = *(const bf16x8*)(Bs + (wx * 64 + i * 16 + (lane & 15)) * 32 + (lane >> 4) * 8);
#pragma unroll
        for (int mi = 0; mi < 4; ++mi)
#pragma unroll
            for (int ni = 0; ni < 4; ++ni)
                acc[mi][ni] = __builtin_amdgcn_mfma_f32_16x16x32_bf16(
                    af[mi], bfr[ni], acc[mi][ni], 0, 0, 0);
    }
    __syncthreads();

    float vv[4], dp[4];
#pragma unroll
    for (int ni = 0; ni < 4; ++ni) {
        int col = n0 + wx * 64 + ni * 16 + (lane & 15);
        vv[ni] = v[col];
        dp[ni] = dproj[b * 1024 + col];
    }
#pragma unroll
    for (int mi = 0; mi < 4; ++mi) {
#pragma unroll
        for (int r = 0; r < 4; ++r) {
            float s = 0.f;
#pragma unroll
            for (int ni = 0; ni < 4; ++ni)
                s += vv[ni] * fast_tanh(acc[mi][ni][r] + dp[ni]);
            s += __shfl_xor(s, 1);
            s += __shfl_xor(s, 2);
            s += __shfl_xor(s, 4);
            s += __shfl_xor(s, 8);
            if ((lane & 15) == 0) {
                int row = wy * 64 + mi * 16 + (lane >> 4) * 4 + r;
                atomicAdd(&esum[row], s);
            }
        }
    }
    __syncthreads();
    if (tid < 128) part[(size_t)n_chunk * M_DIM + m0 + tid] = esum[tid];
}

// ------------- fallback f32-staged GEMM (small ws) --------------------------
__global__ __launch_bounds__(256) void energy_gemm_f32(
        const float* __restrict__ enc, const bf16* __restrict__ WT,
        const float* __restrict__ dproj, const float* __restrict__ v,
        float* __restrict__ part) {
    __shared__ __align__(16) bf16 As[128 * 32];
    __shared__ __align__(16) bf16 Bs[128 * 32];
    __shared__ float esum[128];

    const int tid  = threadIdx.x;
    const int lane = tid & 63;
    const int wave = tid >> 6;
    const int wy = wave >> 1, wx = wave & 1;
    const int L = blockIdx.x;
    const int xcd  = L & 7;
    const int slot = L >> 3;
    const int m_tile = xcd * 64 + (slot >> 3);
    const int n_chunk = slot & 7;
    const int m0 = m_tile * 128;
    const int n0 = n_chunk * 128;
    const int b  = m0 >> 11;

    if (tid < 128) esum[tid] = 0.f;

    floatx4 acc[4][4];
#pragma unroll
    for (int i = 0; i < 4; ++i)
#pragma unroll
        for (int j = 0; j < 4; ++j) acc[i][j] = (floatx4){0.f, 0.f, 0.f, 0.f};

    const int sr = tid >> 2;
    const int sc = (tid & 3) * 8;
    const float* gA = enc + (size_t)(m0 + sr) * 1024 + sc;
    const bf16*  gB = WT  + (size_t)(n0 + sr) * 1024 + sc;
    bf16* lA = As + sr * 32 + sc;
    bf16* lB = Bs + sr * 32 + sc;

    for (int k0 = 0; k0 < K_DIM; k0 += 32) {
        __syncthreads();
#pragma unroll
        for (int rep = 0; rep < 2; ++rep) {
            const float4* p = (const float4*)(gA + (size_t)rep * 64 * 1024 + k0);
            float4 f0 = p[0], f1 = p[1];
            bf16x8 w;
            w[0] = (bf16)f0.x; w[1] = (bf16)f0.y; w[2] = (bf16)f0.z; w[3] = (bf16)f0.w;
            w[4] = (bf16)f1.x; w[5] = (bf16)f1.y; w[6] = (bf16)f1.z; w[7] = (bf16)f1.w;
            *(bf16x8*)(lA + rep * 64 * 32) = w;
            *(bf16x8*)(lB + rep * 64 * 32) =
                *(const bf16x8*)(gB + (size_t)rep * 64 * 1024 + k0);
        }
        __syncthreads();

        bf16x8 af[4], bfr[4];
#pragma unroll
        for (int i = 0; i < 4; ++i)
            af[i] = *(const bf16x8*)(As + (wy * 64 + i * 16 + (lane & 15)) * 32 + (lane >> 4) * 8);
#pragma unroll
        for (int i = 0; i < 4; ++i)
            bfr[i] = *(const bf16x8*)(Bs + (wx * 64 + i * 16 + (lane & 15)) * 32 + (lane >> 4) * 8);
#pragma unroll
        for (int mi = 0; mi < 4; ++mi)
#pragma unroll
            for (int ni = 0; ni < 4; ++ni)
                acc[mi][ni] = __builtin_amdgcn_mfma_f32_16x16x32_bf16(
                    af[mi], bfr[ni], acc[mi][ni], 0, 0, 0);
    }
    __syncthreads();

    float vv[4], dp[4];
#pragma unroll
    for (int ni = 0; ni < 4; ++ni) {
        int col = n0 + wx * 64 + ni * 16 + (lane & 15);
        vv[ni] = v[col];
        dp[ni] = dproj[b * 1024 + col];
    }
#pragma unroll
    for (int mi = 0; mi < 4; ++mi) {
#pragma unroll
        for (int r = 0; r < 4; ++r) {
            float s = 0.f;
#pragma unroll
            for (int ni = 0; ni < 4; ++ni)
                s += vv[ni] * fast_tanh(acc[mi][ni][r] + dp[ni]);
            s += __shfl_xor(s, 1);
            s += __shfl_xor(s, 2);
            s += __shfl_xor(s, 4);
            s += __shfl_xor(s, 8);
            if ((lane & 15) == 0) {
                int row = wy * 64 + mi * 16 + (lane >> 4) * 4 + r;
                atomicAdd(&esum[row], s);
            }
        }
    }
    __syncthreads();
    if (tid < 128) part[(size_t)n_chunk * M_DIM + m0 + tid] = esum[tid];
}

// ------------- masked softmax over T (multiplicative 0/1 mask) --------------
__global__ __launch_bounds__(256) void softmax_kernel(
        const float* __restrict__ part, const int* __restrict__ xlens,
        float* __restrict__ att) {
    const int b = blockIdx.x, tid = threadIdx.x;
    const int len = xlens[b];
    float e[8];
    float mx = -3.4e38f;
#pragma unroll
    for (int i = 0; i < 8; ++i) {
        const int t = tid + i * 256;
        float s = 0.f;
#pragma unroll
        for (int c = 0; c < 8; ++c) s += part[(size_t)c * M_DIM + b * 2048 + t];
        e[i] = (t < len) ? s : 0.f;
        mx = fmaxf(mx, e[i]);
    }
#pragma unroll
    for (int off = 1; off < 64; off <<= 1) mx = fmaxf(mx, __shfl_xor(mx, off));
    __shared__ float sr1[4], sr2[4];
    if ((tid & 63) == 0) sr1[tid >> 6] = mx;
    __syncthreads();
    mx = fmaxf(fmaxf(sr1[0], sr1[1]), fmaxf(sr1[2], sr1[3]));
    float sum = 0.f;
#pragma unroll
    for (int i = 0; i < 8; ++i) { e[i] = __expf(e[i] - mx); sum += e[i]; }
#pragma unroll
    for (int off = 1; off < 64; off <<= 1) sum += __shfl_xor(sum, off);
    if ((tid & 63) == 0) sr2[tid >> 6] = sum;
    __syncthreads();
    sum = sr2[0] + sr2[1] + sr2[2] + sr2[3];
    const float inv = 1.f / sum;
#pragma unroll
    for (int i = 0; i < 8; ++i)
        att[b * 2048 + tid + i * 256] = e[i] * inv;
}

// ------------- context partials: atomic-free, bf16 enc ----------------------
// ctxpart[(b*16+chunk)*1024 + e] = sum over chunk's 128 t of att*encb
__global__ __launch_bounds__(256) void context_part_kernel(
        const bf16* __restrict__ encb, const float* __restrict__ att,
        float* __restrict__ ctxpart) {
    const int b = blockIdx.x, chunk = blockIdx.y, tid = threadIdx.x;
    const int t0 = chunk * 128;
    __shared__ float satt[128];
    if (tid < 128) satt[tid] = att[b * 2048 + t0 + tid];
    __syncthreads();
    const bf16* base = encb + ((size_t)b * 2048 + t0) * 1024 + tid * 4;
    float a0 = 0.f, a1 = 0.f, a2 = 0.f, a3 = 0.f;
#pragma unroll 4
    for (int t = 0; t < 128; ++t) {
        bf16x4 ev = *(const bf16x4*)(base + (size_t)t * 1024);
        float w = satt[t];
        a0 += w * (float)ev[0]; a1 += w * (float)ev[1];
        a2 += w * (float)ev[2]; a3 += w * (float)ev[3];
    }
    float* o = ctxpart + ((size_t)b * 16 + chunk) * 1024 + tid * 4;
    o[0] = a0; o[1] = a1; o[2] = a2; o[3] = a3;
}

__global__ __launch_bounds__(256) void context_reduce_kernel(
        const float* __restrict__ ctxpart, float* __restrict__ out_ctx) {
    const int i = blockIdx.x * 256 + threadIdx.x;     // 0..32767
    const int b = i >> 10, e = i & 1023;
    const float* p = ctxpart + (size_t)b * 16 * 1024 + e;
    float s = 0.f;
#pragma unroll
    for (int c = 0; c < 16; ++c) s += p[c * 1024];
    out_ctx[i] = s;
}

// ------------- fallback context (f32 enc + atomics) -------------------------
__global__ __launch_bounds__(256) void context_kernel_f32(
        const float* __restrict__ enc, const float* __restrict__ att,
        float* __restrict__ ctx) {
    const int b = blockIdx.x, t0 = blockIdx.y * 128, tid = threadIdx.x;
    __shared__ float satt[128];
    if (tid < 128) satt[tid] = att[b * 2048 + t0 + tid];
    __syncthreads();
    const float* base = enc + ((size_t)b * 2048 + t0) * 1024 + tid * 4;
    float a0 = 0.f, a1 = 0.f, a2 = 0.f, a3 = 0.f;
    for (int t = 0; t < 128; ++t) {
        float4 ev = *(const float4*)(base + (size_t)t * 1024);
        float w = satt[t];
        a0 += w * ev.x; a1 += w * ev.y; a2 += w * ev.z; a3 += w * ev.w;
    }
    float* o = ctx + b * 1024 + tid * 4;
    atomicAdd(o + 0, a0); atomicAdd(o + 1, a1);
    atomicAdd(o + 2, a2); atomicAdd(o + 3, a3);
}

extern "C" void kernel_launch(void* const* d_in, const int* in_sizes, int n_in,
                              void* d_out, int out_size, void* d_ws, size_t ws_size,
                              hipStream_t stream) {
    const float* enc   = (const float*)d_in[0];
    const int*   xlens = (const int*)d_in[1];
    const float* dec   = (const float*)d_in[2];
    const float* Wenc  = (const float*)d_in[4];
    const float* benc  = (const float*)d_in[5];
    const float* Wdec  = (const float*)d_in[6];
    const float* v     = (const float*)d_in[7];

    float* out_ctx = (float*)d_out;
    float* out_att = out_ctx + B_DIM * K_DIM;

    char* ws = (char*)d_ws;
    float* dproj   = (float*)ws;                                  // 128 KB
    bf16*  WT      = (bf16*)(ws + (128u << 10));                  // 2 MB
    float* part    = (float*)(ws + (128u << 10) + (2u << 20));    // 2 MB
    bf16*  encb    = (bf16*)(ws + (128u << 10) + (4u << 20));     // 128 MB
    float* ctxpart = (float*)(ws + (128u << 10) + (4u << 20) + (ENC_ELEMS * 2)); // 2 MB
    const size_t need = (128u << 10) + (4u << 20) + ENC_ELEMS * 2 + (2u << 21);

    transpose_wenc<<<dim3(16, 16), 256, 0, stream>>>(Wenc, WT);
    decproj_kernel<<<dim3(B_DIM, 4), 256, 0, stream>>>(dec, Wdec, benc, dproj);

    if (ws_size >= need) {
        cvt_enc<<<2048, 256, 0, stream>>>(enc, encb);
        energy_gemm_bf16<<<4096, 256, 0, stream>>>(encb, WT, dproj, v, part);
        softmax_kernel<<<B_DIM, 256, 0, stream>>>(part, xlens, out_att);
        context_part_kernel<<<dim3(B_DIM, 16), 256, 0, stream>>>(encb, out_att, ctxpart);
        context_reduce_kernel<<<B_DIM * K_DIM / 256, 256, 0, stream>>>(ctxpart, out_ctx);
    } else {
        hipMemsetAsync(out_ctx, 0, B_DIM * K_DIM * sizeof(float), stream);
        energy_gemm_f32<<<4096, 256, 0, stream>>>(enc, WT, dproj, v, part);
        softmax_kernel<<<B_DIM, 256, 0, stream>>>(part, xlens, out_att);
        context_kernel_f32<<<dim3(B_DIM, 16), 256, 0, stream>>>(enc, out_att, out_ctx);
    }
}